// Round 3
// baseline (13236.699 us; speedup 1.0000x reference)
//
#include <hip/hip_runtime.h>
#include <hip/hip_bf16.h>

// RNN_53145925320808 on MI355X (gfx950), 2-layer ReLU RNN + FC.
// R3: ws shrunk 1077MB -> 262MB (bf16 pre0/h1 in-place buffer, gemm1 fused
// into scan1). h-exchange via relaxed AGENT-scope u64 atomics (per-access
// coherent, immune to cross-XCD L2 staleness). ws-guard writes 1e6 beacon.

#define TT 512
#define BB 256
#define HH 1024
#define II 512
#define OO 256

typedef __attribute__((ext_vector_type(4))) float f32x4;
typedef __attribute__((ext_vector_type(8))) short short8;
typedef __attribute__((ext_vector_type(8))) __bf16 bf16x8;
typedef unsigned long long u64;
typedef unsigned int u32;
typedef unsigned short u16;

#define WPL (32*64*64*8)      // shorts per Wih1 fragment-linear plane (2 MiB)
#define PLQ ((BB*HH)/4)       // u64 per exchange plane

__device__ __forceinline__ u16 bf16_rne(float x){
  u32 u = __builtin_bit_cast(u32, x);
  u += 0x7fffu + ((u >> 16) & 1u);
  return (u16)(u >> 16);
}
__device__ __forceinline__ void split2(float x, u16 &hi, u16 &lo){
  hi = bf16_rne(x);
  float hf = __builtin_bit_cast(float, (u32)hi << 16);
  lo = bf16_rne(x - hf);
}
__device__ __forceinline__ float bf16_f(u32 v){
  return __builtin_bit_cast(float, v << 16);
}
__device__ __forceinline__ bf16x8 ld_frag16(const u16* p){
  short8 s = *reinterpret_cast<const short8*>(p);
  return __builtin_bit_cast(bf16x8, s);
}
__device__ __forceinline__ bf16x8 ld_frag_atomic(u64* q){
  u64 q0 = __hip_atomic_load(q,   __ATOMIC_RELAXED, __HIP_MEMORY_SCOPE_AGENT);
  u64 q1 = __hip_atomic_load(q+1, __ATOMIC_RELAXED, __HIP_MEMORY_SCOPE_AGENT);
  union { u64 u[2]; short8 s; } v; v.u[0]=q0; v.u[1]=q1;
  return __builtin_bit_cast(bf16x8, v.s);
}

// ---------------------------------------------------------------------------
// gemm0: pre0 = X @ W_ih0^T + (b_ih0+b_hh0), X fp32 [B,T,I] rows (b*T+t),
// output bf16(rne) stored [t][b][n]. 128x128 tile, BK=32, 4 waves, hi/lo
// split x3 MFMA. LDS fragment-linear -> conflict-free ds_read_b128.
// ---------------------------------------------------------------------------
__global__ __launch_bounds__(256, 1)
void gemm0(const float* __restrict__ X, const float* __restrict__ W,
           const float* __restrict__ b1, const float* __restrict__ b2,
           u16* __restrict__ Out)
{
  constexpr int BK = 32, KT = II / BK;
  __shared__ __align__(16) u16 lA[2][2][128*32];
  __shared__ __align__(16) u16 lB[2][2][128*32];

  const int bid  = blockIdx.x;
  const int nt   = bid & 7;
  const long mt  = bid >> 3;
  const long row_base = mt * 128;
  const int n0   = nt * 128;
  const int tid  = threadIdx.x;
  const int lane = tid & 63;
  const int wave = tid >> 6;
  const int wm = wave >> 1, wn = wave & 1;

  const int sr = tid >> 3;
  const int sk = (tid & 7) << 2;
  const int lq = ((sk >> 3) & 3) << 4;
  const int su = (sk & 7) >> 1;

  f32x4 acc[4][4];
  #pragma unroll
  for (int i=0;i<4;++i)
    #pragma unroll
    for (int j=0;j<4;++j) acc[i][j] = (f32x4)0.f;

  f32x4 va[4], vb[4];

  auto ldAB = [&](int kt){
    #pragma unroll
    for (int it=0; it<4; ++it){
      long m = row_base + it*32 + sr;
      va[it] = *reinterpret_cast<const f32x4*>(X + m*II + (long)kt*BK + sk);
      long n = n0 + it*32 + sr;
      vb[it] = *reinterpret_cast<const f32x4*>(W + n*II + (long)kt*BK + sk);
    }
  };
  auto wrAB = [&](int buf){
    u32* AH = (u32*)lA[buf][0];
    u32* AL = (u32*)lA[buf][1];
    u32* BH = (u32*)lB[buf][0];
    u32* BL = (u32*)lB[buf][1];
    #pragma unroll
    for (int it=0; it<4; ++it){
      int mloc = it*32 + sr;
      int base = ((mloc>>4)*64 + ((mloc&15) | lq))*4 + su;
      u16 h0,l0,h1,l1,h2,l2,h3,l3;
      split2(va[it].x,h0,l0); split2(va[it].y,h1,l1);
      split2(va[it].z,h2,l2); split2(va[it].w,h3,l3);
      AH[base]   = ((u32)h1<<16)|h0;  AH[base+1] = ((u32)h3<<16)|h2;
      AL[base]   = ((u32)l1<<16)|l0;  AL[base+1] = ((u32)l3<<16)|l2;
      u16 g0,m0,g1,m1,g2,m2,g3,m3;
      split2(vb[it].x,g0,m0); split2(vb[it].y,g1,m1);
      split2(vb[it].z,g2,m2); split2(vb[it].w,g3,m3);
      BH[base]   = ((u32)g1<<16)|g0;  BH[base+1] = ((u32)g3<<16)|g2;
      BL[base]   = ((u32)m1<<16)|m0;  BL[base+1] = ((u32)m3<<16)|m2;
    }
  };

  ldAB(0); wrAB(0);
  for (int kt = 0; kt < KT; ++kt){
    __syncthreads();
    const bool more = (kt + 1 < KT);
    if (more) ldAB(kt+1);
    const u16* Ah = lA[kt&1][0];
    const u16* Al = lA[kt&1][1];
    const u16* Bh = lB[kt&1][0];
    const u16* Bl = lB[kt&1][1];
    bf16x8 ah[4], al[4], bh[4], bl[4];
    #pragma unroll
    for (int mi=0; mi<4; ++mi){
      int off = ((wm*4+mi)*64 + lane)*8;
      ah[mi] = ld_frag16(Ah + off);
      al[mi] = ld_frag16(Al + off);
    }
    #pragma unroll
    for (int ni=0; ni<4; ++ni){
      int off = ((wn*4+ni)*64 + lane)*8;
      bh[ni] = ld_frag16(Bh + off);
      bl[ni] = ld_frag16(Bl + off);
    }
    #pragma unroll
    for (int mi=0; mi<4; ++mi)
      #pragma unroll
      for (int ni=0; ni<4; ++ni){
        acc[mi][ni] = __builtin_amdgcn_mfma_f32_16x16x32_bf16(ah[mi], bh[ni], acc[mi][ni], 0,0,0);
        acc[mi][ni] = __builtin_amdgcn_mfma_f32_16x16x32_bf16(ah[mi], bl[ni], acc[mi][ni], 0,0,0);
        acc[mi][ni] = __builtin_amdgcn_mfma_f32_16x16x32_bf16(al[mi], bh[ni], acc[mi][ni], 0,0,0);
      }
    if (more) wrAB((kt+1)&1);
  }

  #pragma unroll
  for (int ni=0; ni<4; ++ni){
    int n = n0 + wn*64 + ni*16 + (lane & 15);
    float bs = b1[n] + b2[n];
    #pragma unroll
    for (int mi=0; mi<4; ++mi){
      #pragma unroll
      for (int j=0; j<4; ++j){
        long r = row_base + wm*64 + mi*16 + ((lane>>4)*4) + j;
        long bb = r >> 9;          // r = b*T + t, T=512
        long t  = r & (TT-1);
        Out[(t*BB + bb)*HH + n] = bf16_rne(acc[mi][ni][j] + bs);
      }
    }
  }
}

// ---------------------------------------------------------------------------
// prep_wih1: W_ih1 fp32 [H,H] -> two bf16 fragment-linear planes (hi, lo),
// per-gn-slice layout [gn(32)][frag(64)][lane(64)][8] so scan1's per-step
// B-fragment loads are coalesced 16B ds-style reads from L2.
// ---------------------------------------------------------------------------
__global__ __launch_bounds__(256)
void prep_wih1(const float* __restrict__ W, u16* __restrict__ Wfl){
  int f  = blockIdx.x*256 + threadIdx.x;   // [0, 1024*128)
  int n  = f >> 7;                          // output col
  int k8 = (f & 127) << 3;                  // k base, 8 wide
  f32x4 w0 = *reinterpret_cast<const f32x4*>(W + (long)n*HH + k8);
  f32x4 w1 = *reinterpret_cast<const f32x4*>(W + (long)n*HH + k8 + 4);
  short8 hs, ls;
  u16 h, l;
  split2(w0.x,h,l); hs[0]=(short)h; ls[0]=(short)l;
  split2(w0.y,h,l); hs[1]=(short)h; ls[1]=(short)l;
  split2(w0.z,h,l); hs[2]=(short)h; ls[2]=(short)l;
  split2(w0.w,h,l); hs[3]=(short)h; ls[3]=(short)l;
  split2(w1.x,h,l); hs[4]=(short)h; ls[4]=(short)l;
  split2(w1.y,h,l); hs[5]=(short)h; ls[5]=(short)l;
  split2(w1.z,h,l); hs[6]=(short)h; ls[6]=(short)l;
  split2(w1.w,h,l); hs[7]=(short)h; ls[7]=(short)l;
  int gn = n >> 5, nl = n & 31;
  int fi = (nl>>4)*32 + (k8>>5);
  int ln = (nl&15) | (((k8>>3)&3)<<4);
  long base = (((long)gn*64 + fi)*64 + ln)*8;
  *reinterpret_cast<short8*>(Wfl + base)        = hs;
  *reinterpret_cast<short8*>(Wfl + WPL + base)  = ls;
}

// ---------------------------------------------------------------------------
// scan<L>: 256 blocks = 8 batch-groups (XCD-local: gm=bid&7) x 32 col-slices.
// W_hh slice hi/lo in LDS (128KB). 4 waves split k (8 chunks of 32 each).
// h exchanged via single-bf16 fragment-linear planes with RELAXED AGENT-scope
// u64 atomics (coherent at MALL, no reliance on wbl2/inv). Group flag barrier.
// L==1 additionally fuses pre1 = h1[t] @ W_ih1^T (A gathered from h1 linear,
// B from prepped fragment-linear planes) into the same accumulators.
// ---------------------------------------------------------------------------
template<int L>
__global__ __launch_bounds__(256, 1)
void scan_rnn(u16* __restrict__ h1,           // [t][b][h] bf16: L0 reads pre0/writes h1 in place; L1 reads h1
              const float* __restrict__ Whh,
              const u16* __restrict__ Wfl,    // L1 only
              const float* __restrict__ bih,  // L1 only
              const float* __restrict__ bhh,  // L1 only
              u64* PhQ, u32* ctr, float* __restrict__ h_last)
{
  __shared__ __align__(16) u16 lWh[32*1024];
  __shared__ __align__(16) u16 lWl[32*1024];
  __shared__ __align__(16) float lred[4][32][36];

  const int bid = blockIdx.x;
  const int gm = bid & 7;        // batch group -> XCD-local under bid%8 round-robin
  const int gn = bid >> 3;       // col slice
  const int tid = threadIdx.x;
  const int lane = tid & 63;
  const int kq = tid >> 6;

  { // stage W_hh slice -> LDS hi/lo fragment-linear
    u32* WH = (u32*)lWh;
    u32* WL = (u32*)lWl;
    #pragma unroll 4
    for (int it=0; it<32; ++it){
      int f = it*256 + tid;
      int nl = f >> 8;
      int k4 = (f & 255) << 2;
      f32x4 w = *reinterpret_cast<const f32x4*>(Whh + (long)(gn*32 + nl)*HH + k4);
      int base = (((nl>>4)*32 + (k4>>5))*64 + ((nl&15) | (((k4>>3)&3)<<4)))*4 + ((k4&7)>>1);
      u16 h0,l0,h1_,l1,h2,l2,h3,l3;
      split2(w.x,h0,l0); split2(w.y,h1_,l1); split2(w.z,h2,l2); split2(w.w,h3,l3);
      WH[base]   = ((u32)h1_<<16)|h0;  WH[base+1] = ((u32)h3<<16)|h2;
      WL[base]   = ((u32)l1<<16)|l0;   WL[base+1] = ((u32)l3<<16)|l2;
    }
  }
  __syncthreads();

  const int fr  = tid >> 3;
  const int fcl = (tid & 7) << 2;
  const long b_out = gm*32 + fr;
  const int  n_out = gn*32 + fcl;
  const long plq = (long)((((b_out>>4)*32 + (n_out>>5))*64
                    + ((b_out&15) | (((n_out>>3)&3)<<4)))*8 + (n_out&7)) >> 2;
  u32* ctr_g = ctr + gm*16;

  const int r_lane = lane & 15;
  const int kg8    = (lane >> 4) * 8;
  long rowoff[2];
  #pragma unroll
  for (int mi=0; mi<2; ++mi)
    rowoff[mi] = (long)((gm*2+mi)*16 + r_lane)*HH + kg8;

  f32x4 bias = (f32x4)0.f;
  if constexpr (L == 1){
    f32x4 b1v = *reinterpret_cast<const f32x4*>(bih + n_out);
    f32x4 b2v = *reinterpret_cast<const f32x4*>(bhh + n_out);
    bias = b1v + b2v;
  }

  for (int t=0; t<TT; ++t){
    const long pbase = (long)t * BB * HH;
    float p0=0.f,p1=0.f,p2=0.f,p3=0.f;
    if constexpr (L == 0){
      u64 pv = *reinterpret_cast<const u64*>(h1 + pbase + b_out*HH + n_out);
      p0 = bf16_f((u32)(pv & 0xffff));
      p1 = bf16_f((u32)((pv>>16) & 0xffff));
      p2 = bf16_f((u32)((pv>>32) & 0xffff));
      p3 = bf16_f((u32)((pv>>48) & 0xffff));
    }
    const int wb = t & 1, rb = wb ^ 1;

    f32x4 acc[2][2];
    acc[0][0]=(f32x4)0.f; acc[0][1]=(f32x4)0.f; acc[1][0]=(f32x4)0.f; acc[1][1]=(f32x4)0.f;

    if constexpr (L == 1){
      // fused pre1 = h1[t] @ W_ih1^T  (bf16 A x hi/lo B)
      #pragma unroll
      for (int kc=0; kc<8; ++kc){
        const int kcg = kq*8 + kc;
        bf16x8 a1[2], wh[2], wl[2];
        #pragma unroll
        for (int mi=0; mi<2; ++mi)
          a1[mi] = ld_frag16(h1 + pbase + rowoff[mi] + kcg*32);
        #pragma unroll
        for (int ni=0; ni<2; ++ni){
          long woff = (((long)gn*64 + (ni*32 + kcg))*64 + lane)*8;
          wh[ni] = ld_frag16(Wfl + woff);
          wl[ni] = ld_frag16(Wfl + WPL + woff);
        }
        #pragma unroll
        for (int mi=0; mi<2; ++mi)
          #pragma unroll
          for (int ni=0; ni<2; ++ni){
            acc[mi][ni] = __builtin_amdgcn_mfma_f32_16x16x32_bf16(a1[mi], wh[ni], acc[mi][ni],0,0,0);
            acc[mi][ni] = __builtin_amdgcn_mfma_f32_16x16x32_bf16(a1[mi], wl[ni], acc[mi][ni],0,0,0);
          }
      }
    }

    if (t > 0){
      u64* Aq = PhQ + (long)rb*PLQ;
      #pragma unroll
      for (int kc=0; kc<8; ++kc){
        const int kcg = kq*8 + kc;
        bf16x8 a2[2], bh[2], bl[2];
        #pragma unroll
        for (int mi=0; mi<2; ++mi)
          a2[mi] = ld_frag_atomic(Aq + ((long)((gm*2+mi)*32 + kcg)*64 + lane)*2);
        #pragma unroll
        for (int ni=0; ni<2; ++ni){
          int off = ((ni*32 + kcg)*64 + lane)*8;
          bh[ni] = ld_frag16(lWh + off);
          bl[ni] = ld_frag16(lWl + off);
        }
        #pragma unroll
        for (int mi=0; mi<2; ++mi)
          #pragma unroll
          for (int ni=0; ni<2; ++ni){
            acc[mi][ni] = __builtin_amdgcn_mfma_f32_16x16x32_bf16(a2[mi], bh[ni], acc[mi][ni],0,0,0);
            acc[mi][ni] = __builtin_amdgcn_mfma_f32_16x16x32_bf16(a2[mi], bl[ni], acc[mi][ni],0,0,0);
          }
      }
    }

    const bool red = (L == 1) || (t > 0);
    if (red){
      #pragma unroll
      for (int mi=0; mi<2; ++mi)
        #pragma unroll
        for (int ni=0; ni<2; ++ni)
          #pragma unroll
          for (int j=0; j<4; ++j)
            lred[kq][mi*16 + (lane>>4)*4 + j][ni*16 + (lane&15)] = acc[mi][ni][j];
    }
    __syncthreads();

    float s0=0.f, s1=0.f, s2=0.f, s3=0.f;
    if (red){
      #pragma unroll
      for (int w=0; w<4; ++w){
        const f32x4 v = *reinterpret_cast<const f32x4*>(&lred[w][fr][fcl]);
        s0 += v.x; s1 += v.y; s2 += v.z; s3 += v.w;
      }
    }
    float h0, h1v, h2, h3;
    if constexpr (L == 0){
      h0 = fmaxf(s0 + p0, 0.f); h1v = fmaxf(s1 + p1, 0.f);
      h2 = fmaxf(s2 + p2, 0.f); h3  = fmaxf(s3 + p3, 0.f);
    } else {
      h0 = fmaxf(s0 + bias.x, 0.f); h1v = fmaxf(s1 + bias.y, 0.f);
      h2 = fmaxf(s2 + bias.z, 0.f); h3  = fmaxf(s3 + bias.w, 0.f);
    }
    const u64 hv = (u64)bf16_rne(h0) | ((u64)bf16_rne(h1v)<<16)
                 | ((u64)bf16_rne(h2)<<32) | ((u64)bf16_rne(h3)<<48);
    __hip_atomic_store(PhQ + (long)wb*PLQ + plq, hv,
                       __ATOMIC_RELAXED, __HIP_MEMORY_SCOPE_AGENT);
    if constexpr (L == 0){
      *reinterpret_cast<u64*>(h1 + pbase + b_out*HH + n_out) = hv;  // in place over pre0
    } else {
      if (t == TT-1){
        f32x4 hvv; hvv.x=h0; hvv.y=h1v; hvv.z=h2; hvv.w=h3;
        *reinterpret_cast<f32x4*>(h_last + b_out*HH + n_out) = hvv;
      }
    }
    __syncthreads();   // drains all waves' stores (vmcnt) before release
    if (tid == 0){
      __hip_atomic_fetch_add(ctr_g, 1u, __ATOMIC_RELEASE, __HIP_MEMORY_SCOPE_AGENT);
      const u32 tgt = 32u * (u32)(t+1);
      while (__hip_atomic_load(ctr_g, __ATOMIC_ACQUIRE, __HIP_MEMORY_SCOPE_AGENT) < tgt){
        __builtin_amdgcn_s_sleep(1);
      }
    }
    __syncthreads();
  }
}

__global__ void init_ws(u32* ctr){ ctr[threadIdx.x] = 0u; }

__global__ __launch_bounds__(256)
void beacon(float* out, int n){
  for (int i = blockIdx.x*256 + threadIdx.x; i < n; i += 256*256) out[i] = 1.0e6f;
}

__global__ __launch_bounds__(256)
void fc_k(const float* __restrict__ h, const float* __restrict__ w,
          const float* __restrict__ bsc, float* __restrict__ out){
  const int b = blockIdx.x;
  const int o = threadIdx.x;
  const f32x4* hp = reinterpret_cast<const f32x4*>(h + (long)b*HH);
  const f32x4* wp = reinterpret_cast<const f32x4*>(w + (long)o*HH);
  float acc = 0.f;
  #pragma unroll 8
  for (int i=0; i<HH/4; ++i){
    f32x4 a = hp[i], c = wp[i];
    acc += a.x*c.x + a.y*c.y + a.z*c.z + a.w*c.w;
  }
  out[(long)b*OO + o] = acc + bsc[o];
}

extern "C" void kernel_launch(void* const* d_in, const int* in_sizes, int n_in,
                              void* d_out, int out_size, void* d_ws, size_t ws_size,
                              hipStream_t stream)
{
  const float* X    = (const float*)d_in[0];
  const float* Wih0 = (const float*)d_in[1];
  const float* Whh0 = (const float*)d_in[2];
  const float* bih0 = (const float*)d_in[3];
  const float* bhh0 = (const float*)d_in[4];
  const float* Wih1 = (const float*)d_in[5];
  const float* Whh1 = (const float*)d_in[6];
  const float* bih1 = (const float*)d_in[7];
  const float* bhh1 = (const float*)d_in[8];
  const float* fcw  = (const float*)d_in[9];
  const float* fcb  = (const float*)d_in[10];
  float* out = (float*)d_out;
  char* ws = (char*)d_ws;

  size_t off = 0;
  u16* H1  = (u16*)(ws + off); off += (size_t)TT*BB*HH*2;   // 256 MiB: pre0 -> h1 (bf16)
  u16* WFL = (u16*)(ws + off); off += (size_t)2*WPL*2;      // 4 MiB: Wih1 hi/lo planes
  u64* PH  = (u64*)(ws + off); off += (size_t)2*PLQ*8;      // 1 MiB: exchange planes
  float* HL = (float*)(ws + off); off += (size_t)BB*HH*4;   // 1 MiB
  u32* CT  = (u32*)(ws + off); off += 1024;                 // 256 counters

  if (ws_size < off){   // ws too small: write 1e6 beacon -> absmax ~1e6 signals this path
    beacon<<<dim3(256), dim3(256), 0, stream>>>(out, out_size);
    return;
  }

  init_ws<<<dim3(1), dim3(256), 0, stream>>>(CT);
  prep_wih1<<<dim3(512), dim3(256), 0, stream>>>(Wih1, WFL);
  gemm0<<<dim3((131072/128)*(HH/128)), dim3(256), 0, stream>>>(X, Wih0, bih0, bhh0, H1);
  scan_rnn<0><<<dim3(256), dim3(256), 0, stream>>>(H1, Whh0, nullptr, nullptr, nullptr,
                                                   PH, CT, nullptr);
  scan_rnn<1><<<dim3(256), dim3(256), 0, stream>>>(H1, Whh1, WFL, bih1, bhh1,
                                                   PH, CT + 128, HL);
  fc_k<<<dim3(BB), dim3(OO), 0, stream>>>(HL, fcw, fcb, out);
}

// Round 4
// 10293.162 us; speedup vs baseline: 1.2860x; 1.2860x over previous
//
#include <hip/hip_runtime.h>
#include <hip/hip_bf16.h>

// RNN_53145925320808 on MI355X (gfx950), 2-layer ReLU RNN + FC.
// R4: (1) flag barrier spins RELAXED (R3's per-poll ACQUIRE emitted L1/L2
// invalidate every poll -> 12.4us/step all-stall). Producer release on the
// fetch_add only (one wbl2/step). Exchange data stays on relaxed agent-scope
// atomics (MALL coherent). (2) L1 prefetches next-step A-fragments across the
// barrier. (3) gemm0 LDS staging XOR-swizzled (write+read) -> kills 4-way
// bank conflicts (SQ_LDS_BANK_CONFLICT was 1.0e8).

#define TT 512
#define BB 256
#define HH 1024
#define II 512
#define OO 256

typedef __attribute__((ext_vector_type(4))) float f32x4;
typedef __attribute__((ext_vector_type(8))) short short8;
typedef __attribute__((ext_vector_type(8))) __bf16 bf16x8;
typedef unsigned long long u64;
typedef unsigned int u32;
typedef unsigned short u16;

#define WPL (32*64*64*8)      // shorts per Wih1 fragment-linear plane (2 MiB)
#define PLQ ((BB*HH)/4)       // u64 per exchange plane

__device__ __forceinline__ u16 bf16_rne(float x){
  u32 u = __builtin_bit_cast(u32, x);
  u += 0x7fffu + ((u >> 16) & 1u);
  return (u16)(u >> 16);
}
__device__ __forceinline__ void split2(float x, u16 &hi, u16 &lo){
  hi = bf16_rne(x);
  float hf = __builtin_bit_cast(float, (u32)hi << 16);
  lo = bf16_rne(x - hf);
}
__device__ __forceinline__ float bf16_f(u32 v){
  return __builtin_bit_cast(float, v << 16);
}
__device__ __forceinline__ bf16x8 ld_frag16(const u16* p){
  short8 s = *reinterpret_cast<const short8*>(p);
  return __builtin_bit_cast(bf16x8, s);
}
__device__ __forceinline__ bf16x8 ld_frag_atomic(u64* q){
  u64 q0 = __hip_atomic_load(q,   __ATOMIC_RELAXED, __HIP_MEMORY_SCOPE_AGENT);
  u64 q1 = __hip_atomic_load(q+1, __ATOMIC_RELAXED, __HIP_MEMORY_SCOPE_AGENT);
  union { u64 u[2]; short8 s; } v; v.u[0]=q0; v.u[1]=q1;
  return __builtin_bit_cast(bf16x8, v.s);
}
__device__ __forceinline__ u64 pack4(u16 a, u16 b, u16 c, u16 d){
  return (u64)(((u32)b<<16)|a) | ((u64)(((u32)d<<16)|c) << 32);
}
__device__ __forceinline__ int swz(int byte){  // mix k-group bits (8-9) into bank bits (4-5)
  return byte ^ (((byte >> 8) & 3) << 4);
}

// ---------------------------------------------------------------------------
// gemm0: pre0 = X @ W_ih0^T + (b_ih0+b_hh0), X fp32 [B,T,I] rows (b*T+t),
// output bf16(rne) stored [t][b][n]. 128x128 tile, BK=32, 4 waves, hi/lo
// split x3 MFMA. LDS fragment-linear + XOR-swizzle -> conflict-free.
// ---------------------------------------------------------------------------
__global__ __launch_bounds__(256, 1)
void gemm0(const float* __restrict__ X, const float* __restrict__ W,
           const float* __restrict__ b1, const float* __restrict__ b2,
           u16* __restrict__ Out)
{
  constexpr int BK = 32, KT = II / BK;
  __shared__ __align__(16) u16 lA[2][2][128*32];
  __shared__ __align__(16) u16 lB[2][2][128*32];

  const int bid  = blockIdx.x;
  const int nt   = bid & 7;
  const long mt  = bid >> 3;
  const long row_base = mt * 128;
  const int n0   = nt * 128;
  const int tid  = threadIdx.x;
  const int lane = tid & 63;
  const int wave = tid >> 6;
  const int wm = wave >> 1, wn = wave & 1;

  const int sr = tid >> 3;
  const int sk = (tid & 7) << 2;
  const int lq = ((sk >> 3) & 3) << 4;
  const int su = (sk & 7) >> 1;        // u32 slot within lane: 0 or 2

  f32x4 acc[4][4];
  #pragma unroll
  for (int i=0;i<4;++i)
    #pragma unroll
    for (int j=0;j<4;++j) acc[i][j] = (f32x4)0.f;

  f32x4 va[4], vb[4];

  auto ldAB = [&](int kt){
    #pragma unroll
    for (int it=0; it<4; ++it){
      long m = row_base + it*32 + sr;
      va[it] = *reinterpret_cast<const f32x4*>(X + m*II + (long)kt*BK + sk);
      long n = n0 + it*32 + sr;
      vb[it] = *reinterpret_cast<const f32x4*>(W + n*II + (long)kt*BK + sk);
    }
  };
  auto wrAB = [&](int buf){
    char* AH = (char*)lA[buf][0];
    char* AL = (char*)lA[buf][1];
    char* BH = (char*)lB[buf][0];
    char* BL = (char*)lB[buf][1];
    #pragma unroll
    for (int it=0; it<4; ++it){
      int mloc = it*32 + sr;
      int byt = (mloc>>4)*1024 + ((mloc&15)|lq)*16 + su*4;   // 8B aligned
      int bs = swz(byt);
      u16 h0,l0,h1,l1,h2,l2,h3,l3;
      split2(va[it].x,h0,l0); split2(va[it].y,h1,l1);
      split2(va[it].z,h2,l2); split2(va[it].w,h3,l3);
      *reinterpret_cast<u64*>(AH + bs) = pack4(h0,h1,h2,h3);
      *reinterpret_cast<u64*>(AL + bs) = pack4(l0,l1,l2,l3);
      u16 g0,m0,g1,m1,g2,m2,g3,m3;
      split2(vb[it].x,g0,m0); split2(vb[it].y,g1,m1);
      split2(vb[it].z,g2,m2); split2(vb[it].w,g3,m3);
      *reinterpret_cast<u64*>(BH + bs) = pack4(g0,g1,g2,g3);
      *reinterpret_cast<u64*>(BL + bs) = pack4(m0,m1,m2,m3);
    }
  };

  ldAB(0); wrAB(0);
  for (int kt = 0; kt < KT; ++kt){
    __syncthreads();
    const bool more = (kt + 1 < KT);
    if (more) ldAB(kt+1);
    const char* Ah = (const char*)lA[kt&1][0];
    const char* Al = (const char*)lA[kt&1][1];
    const char* Bh = (const char*)lB[kt&1][0];
    const char* Bl = (const char*)lB[kt&1][1];
    bf16x8 ah[4], al[4], bh[4], bl[4];
    #pragma unroll
    for (int mi=0; mi<4; ++mi){
      int ob = swz(((wm*4+mi)*64 + lane)*16);
      ah[mi] = ld_frag16((const u16*)(Ah + ob));
      al[mi] = ld_frag16((const u16*)(Al + ob));
    }
    #pragma unroll
    for (int ni=0; ni<4; ++ni){
      int ob = swz(((wn*4+ni)*64 + lane)*16);
      bh[ni] = ld_frag16((const u16*)(Bh + ob));
      bl[ni] = ld_frag16((const u16*)(Bl + ob));
    }
    #pragma unroll
    for (int mi=0; mi<4; ++mi)
      #pragma unroll
      for (int ni=0; ni<4; ++ni){
        acc[mi][ni] = __builtin_amdgcn_mfma_f32_16x16x32_bf16(ah[mi], bh[ni], acc[mi][ni], 0,0,0);
        acc[mi][ni] = __builtin_amdgcn_mfma_f32_16x16x32_bf16(ah[mi], bl[ni], acc[mi][ni], 0,0,0);
        acc[mi][ni] = __builtin_amdgcn_mfma_f32_16x16x32_bf16(al[mi], bh[ni], acc[mi][ni], 0,0,0);
      }
    if (more) wrAB((kt+1)&1);
  }

  #pragma unroll
  for (int ni=0; ni<4; ++ni){
    int n = n0 + wn*64 + ni*16 + (lane & 15);
    float bs = b1[n] + b2[n];
    #pragma unroll
    for (int mi=0; mi<4; ++mi){
      #pragma unroll
      for (int j=0; j<4; ++j){
        long r = row_base + wm*64 + mi*16 + ((lane>>4)*4) + j;
        long bb = r >> 9;          // r = b*T + t, T=512
        long t  = r & (TT-1);
        Out[(t*BB + bb)*HH + n] = bf16_rne(acc[mi][ni][j] + bs);
      }
    }
  }
}

// ---------------------------------------------------------------------------
// prep_wih1: W_ih1 fp32 [H,H] -> two bf16 fragment-linear planes (hi, lo).
// ---------------------------------------------------------------------------
__global__ __launch_bounds__(256)
void prep_wih1(const float* __restrict__ W, u16* __restrict__ Wfl){
  int f  = blockIdx.x*256 + threadIdx.x;   // [0, 1024*128)
  int n  = f >> 7;
  int k8 = (f & 127) << 3;
  f32x4 w0 = *reinterpret_cast<const f32x4*>(W + (long)n*HH + k8);
  f32x4 w1 = *reinterpret_cast<const f32x4*>(W + (long)n*HH + k8 + 4);
  short8 hs, ls;
  u16 h, l;
  split2(w0.x,h,l); hs[0]=(short)h; ls[0]=(short)l;
  split2(w0.y,h,l); hs[1]=(short)h; ls[1]=(short)l;
  split2(w0.z,h,l); hs[2]=(short)h; ls[2]=(short)l;
  split2(w0.w,h,l); hs[3]=(short)h; ls[3]=(short)l;
  split2(w1.x,h,l); hs[4]=(short)h; ls[4]=(short)l;
  split2(w1.y,h,l); hs[5]=(short)h; ls[5]=(short)l;
  split2(w1.z,h,l); hs[6]=(short)h; ls[6]=(short)l;
  split2(w1.w,h,l); hs[7]=(short)h; ls[7]=(short)l;
  int gn = n >> 5, nl = n & 31;
  int fi = (nl>>4)*32 + (k8>>5);
  int ln = (nl&15) | (((k8>>3)&3)<<4);
  long base = (((long)gn*64 + fi)*64 + ln)*8;
  *reinterpret_cast<short8*>(Wfl + base)        = hs;
  *reinterpret_cast<short8*>(Wfl + WPL + base)  = ls;
}

// ---------------------------------------------------------------------------
// scan<L>: 256 blocks = 8 batch-groups x 32 col-slices. W_hh slice hi/lo in
// LDS. h exchanged via fragment-linear bf16 planes (relaxed agent atomics =
// MALL-coherent). Flag barrier: fetch_add(RELEASE) once/step, RELAXED spin.
// L==1 fuses pre1 = h1[t] @ W_ih1^T with A-fragments prefetched across steps.
// ---------------------------------------------------------------------------
template<int L>
__global__ __launch_bounds__(256, 1)
void scan_rnn(u16* __restrict__ h1,
              const float* __restrict__ Whh,
              const u16* __restrict__ Wfl,
              const float* __restrict__ bih,
              const float* __restrict__ bhh,
              u64* PhQ, u32* ctr, float* __restrict__ h_last)
{
  __shared__ __align__(16) u16 lWh[32*1024];
  __shared__ __align__(16) u16 lWl[32*1024];
  __shared__ __align__(16) float lred[4][32][36];

  const int bid = blockIdx.x;
  const int gm = bid & 7;        // batch group -> XCD-local under bid%8 round-robin
  const int gn = bid >> 3;       // col slice
  const int tid = threadIdx.x;
  const int lane = tid & 63;
  const int kq = tid >> 6;

  { // stage W_hh slice -> LDS hi/lo fragment-linear (one-time)
    u32* WH = (u32*)lWh;
    u32* WL = (u32*)lWl;
    #pragma unroll 4
    for (int it=0; it<32; ++it){
      int f = it*256 + tid;
      int nl = f >> 8;
      int k4 = (f & 255) << 2;
      f32x4 w = *reinterpret_cast<const f32x4*>(Whh + (long)(gn*32 + nl)*HH + k4);
      int base = (((nl>>4)*32 + (k4>>5))*64 + ((nl&15) | (((k4>>3)&3)<<4)))*4 + ((k4&7)>>1);
      u16 h0,l0,h1_,l1,h2,l2,h3,l3;
      split2(w.x,h0,l0); split2(w.y,h1_,l1); split2(w.z,h2,l2); split2(w.w,h3,l3);
      WH[base]   = ((u32)h1_<<16)|h0;  WH[base+1] = ((u32)h3<<16)|h2;
      WL[base]   = ((u32)l1<<16)|l0;   WL[base+1] = ((u32)l3<<16)|l2;
    }
  }
  __syncthreads();

  const int fr  = tid >> 3;
  const int fcl = (tid & 7) << 2;
  const long b_out = gm*32 + fr;
  const int  n_out = gn*32 + fcl;
  const long plq = (long)((((b_out>>4)*32 + (n_out>>5))*64
                    + ((b_out&15) | (((n_out>>3)&3)<<4)))*8 + (n_out&7)) >> 2;
  u32* ctr_g = ctr + gm*16;

  const int r_lane = lane & 15;
  const int kg8    = (lane >> 4) * 8;
  long rowoff[2];
  #pragma unroll
  for (int mi=0; mi<2; ++mi)
    rowoff[mi] = (long)((gm*2+mi)*16 + r_lane)*HH + kg8;

  f32x4 bias = (f32x4)0.f;
  if constexpr (L == 1){
    f32x4 b1v = *reinterpret_cast<const f32x4*>(bih + n_out);
    f32x4 b2v = *reinterpret_cast<const f32x4*>(bhh + n_out);
    bias = b1v + b2v;
  }

  // L1: A-fragments of h1[t], prefetched one step ahead (no cross-block dep)
  bf16x8 a1r[2][8];
  auto ld_a1 = [&](int t){
    const long pb = (long)t * BB * HH;
    #pragma unroll
    for (int kc=0; kc<8; ++kc)
      #pragma unroll
      for (int mi=0; mi<2; ++mi)
        a1r[mi][kc] = ld_frag16(h1 + pb + rowoff[mi] + (kq*8+kc)*32);
  };
  if constexpr (L == 1) ld_a1(0);

  for (int t=0; t<TT; ++t){
    const long pbase = (long)t * BB * HH;
    float p0=0.f,p1=0.f,p2=0.f,p3=0.f;
    if constexpr (L == 0){
      u64 pv = *reinterpret_cast<const u64*>(h1 + pbase + b_out*HH + n_out);
      p0 = bf16_f((u32)(pv & 0xffff));
      p1 = bf16_f((u32)((pv>>16) & 0xffff));
      p2 = bf16_f((u32)((pv>>32) & 0xffff));
      p3 = bf16_f((u32)((pv>>48) & 0xffff));
    }
    const int wb = t & 1, rb = wb ^ 1;

    f32x4 acc[2][2];
    acc[0][0]=(f32x4)0.f; acc[0][1]=(f32x4)0.f; acc[1][0]=(f32x4)0.f; acc[1][1]=(f32x4)0.f;

    if (t > 0){   // recurrent term: h_{t-1} @ W_hh^T (hi/lo B x2 MFMA)
      u64* Aq = PhQ + (long)rb*PLQ;
      #pragma unroll
      for (int kc=0; kc<8; ++kc){
        const int kcg = kq*8 + kc;
        bf16x8 a2[2], bh[2], bl[2];
        #pragma unroll
        for (int mi=0; mi<2; ++mi)
          a2[mi] = ld_frag_atomic(Aq + ((long)((gm*2+mi)*32 + kcg)*64 + lane)*2);
        #pragma unroll
        for (int ni=0; ni<2; ++ni){
          int off = ((ni*32 + kcg)*64 + lane)*8;
          bh[ni] = ld_frag16(lWh + off);
          bl[ni] = ld_frag16(lWl + off);
        }
        #pragma unroll
        for (int mi=0; mi<2; ++mi)
          #pragma unroll
          for (int ni=0; ni<2; ++ni){
            acc[mi][ni] = __builtin_amdgcn_mfma_f32_16x16x32_bf16(a2[mi], bh[ni], acc[mi][ni],0,0,0);
            acc[mi][ni] = __builtin_amdgcn_mfma_f32_16x16x32_bf16(a2[mi], bl[ni], acc[mi][ni],0,0,0);
          }
      }
    }

    if constexpr (L == 1){   // fused pre1 = h1[t] @ W_ih1^T (prefetched A)
      #pragma unroll
      for (int kc=0; kc<8; ++kc){
        const int kcg = kq*8 + kc;
        bf16x8 wh[2], wl[2];
        #pragma unroll
        for (int ni=0; ni<2; ++ni){
          long woff = (((long)gn*64 + (ni*32 + kcg))*64 + lane)*8;
          wh[ni] = ld_frag16(Wfl + woff);
          wl[ni] = ld_frag16(Wfl + WPL + woff);
        }
        #pragma unroll
        for (int mi=0; mi<2; ++mi)
          #pragma unroll
          for (int ni=0; ni<2; ++ni){
            acc[mi][ni] = __builtin_amdgcn_mfma_f32_16x16x32_bf16(a1r[mi][kc], wh[ni], acc[mi][ni],0,0,0);
            acc[mi][ni] = __builtin_amdgcn_mfma_f32_16x16x32_bf16(a1r[mi][kc], wl[ni], acc[mi][ni],0,0,0);
          }
      }
      if (t + 1 < TT) ld_a1(t+1);   // prefetch next step's A, hidden under finish+barrier
    }

    const bool red = (L == 1) || (t > 0);
    if (red){
      #pragma unroll
      for (int mi=0; mi<2; ++mi)
        #pragma unroll
        for (int ni=0; ni<2; ++ni)
          #pragma unroll
          for (int j=0; j<4; ++j)
            lred[kq][mi*16 + (lane>>4)*4 + j][ni*16 + (lane&15)] = acc[mi][ni][j];
    }
    __syncthreads();

    float s0=0.f, s1=0.f, s2=0.f, s3=0.f;
    if (red){
      #pragma unroll
      for (int w=0; w<4; ++w){
        const f32x4 v = *reinterpret_cast<const f32x4*>(&lred[w][fr][fcl]);
        s0 += v.x; s1 += v.y; s2 += v.z; s3 += v.w;
      }
    }
    float h0, h1v, h2, h3;
    if constexpr (L == 0){
      h0 = fmaxf(s0 + p0, 0.f); h1v = fmaxf(s1 + p1, 0.f);
      h2 = fmaxf(s2 + p2, 0.f); h3  = fmaxf(s3 + p3, 0.f);
    } else {
      h0 = fmaxf(s0 + bias.x, 0.f); h1v = fmaxf(s1 + bias.y, 0.f);
      h2 = fmaxf(s2 + bias.z, 0.f); h3  = fmaxf(s3 + bias.w, 0.f);
    }
    const u64 hv = (u64)bf16_rne(h0) | ((u64)bf16_rne(h1v)<<16)
                 | ((u64)bf16_rne(h2)<<32) | ((u64)bf16_rne(h3)<<48);
    __hip_atomic_store(PhQ + (long)wb*PLQ + plq, hv,
                       __ATOMIC_RELAXED, __HIP_MEMORY_SCOPE_AGENT);
    if constexpr (L == 0){
      *reinterpret_cast<u64*>(h1 + pbase + b_out*HH + n_out) = hv;  // in place over pre0
    } else {
      if (t == TT-1){
        f32x4 hvv; hvv.x=h0; hvv.y=h1v; hvv.z=h2; hvv.w=h3;
        *reinterpret_cast<f32x4*>(h_last + b_out*HH + n_out) = hvv;
      }
    }
    __syncthreads();   // all waves' stores drained (vmcnt0) before leader releases
    if (tid == 0){
      // RELEASE add: one wbl2/step. Spin RELAXED: no per-poll cache inv.
      __hip_atomic_fetch_add(ctr_g, 1u, __ATOMIC_RELEASE, __HIP_MEMORY_SCOPE_AGENT);
      const u32 tgt = 32u * (u32)(t+1);
      while (__hip_atomic_load(ctr_g, __ATOMIC_RELAXED, __HIP_MEMORY_SCOPE_AGENT) < tgt){
        __builtin_amdgcn_s_sleep(1);
      }
      __atomic_signal_fence(__ATOMIC_ACQUIRE);  // compiler-order only; HW is in-order issue
    }
    __syncthreads();
  }
}

__global__ void init_ws(u32* ctr){ ctr[threadIdx.x] = 0u; }

__global__ __launch_bounds__(256)
void beacon(float* out, int n){
  for (int i = blockIdx.x*256 + threadIdx.x; i < n; i += 256*256) out[i] = 1.0e6f;
}

__global__ __launch_bounds__(256)
void fc_k(const float* __restrict__ h, const float* __restrict__ w,
          const float* __restrict__ bsc, float* __restrict__ out){
  const int b = blockIdx.x;
  const int o = threadIdx.x;
  const f32x4* hp = reinterpret_cast<const f32x4*>(h + (long)b*HH);
  const f32x4* wp = reinterpret_cast<const f32x4*>(w + (long)o*HH);
  float acc = 0.f;
  #pragma unroll 8
  for (int i=0; i<HH/4; ++i){
    f32x4 a = hp[i], c = wp[i];
    acc += a.x*c.x + a.y*c.y + a.z*c.z + a.w*c.w;
  }
  out[(long)b*OO + o] = acc + bsc[o];
}

extern "C" void kernel_launch(void* const* d_in, const int* in_sizes, int n_in,
                              void* d_out, int out_size, void* d_ws, size_t ws_size,
                              hipStream_t stream)
{
  const float* X    = (const float*)d_in[0];
  const float* Wih0 = (const float*)d_in[1];
  const float* Whh0 = (const float*)d_in[2];
  const float* bih0 = (const float*)d_in[3];
  const float* bhh0 = (const float*)d_in[4];
  const float* Wih1 = (const float*)d_in[5];
  const float* Whh1 = (const float*)d_in[6];
  const float* bih1 = (const float*)d_in[7];
  const float* bhh1 = (const float*)d_in[8];
  const float* fcw  = (const float*)d_in[9];
  const float* fcb  = (const float*)d_in[10];
  float* out = (float*)d_out;
  char* ws = (char*)d_ws;

  size_t off = 0;
  u16* H1  = (u16*)(ws + off); off += (size_t)TT*BB*HH*2;   // 256 MiB: pre0 -> h1 (bf16)
  u16* WFL = (u16*)(ws + off); off += (size_t)2*WPL*2;      // 4 MiB: Wih1 hi/lo planes
  u64* PH  = (u64*)(ws + off); off += (size_t)2*PLQ*8;      // 1 MiB: exchange planes
  float* HL = (float*)(ws + off); off += (size_t)BB*HH*4;   // 1 MiB
  u32* CT  = (u32*)(ws + off); off += 1024;                 // 256 counters

  if (ws_size < off){   // ws too small: 1e6 beacon signals this path distinctly
    beacon<<<dim3(256), dim3(256), 0, stream>>>(out, out_size);
    return;
  }

  init_ws<<<dim3(1), dim3(256), 0, stream>>>(CT);
  prep_wih1<<<dim3(512), dim3(256), 0, stream>>>(Wih1, WFL);
  gemm0<<<dim3((131072/128)*(HH/128)), dim3(256), 0, stream>>>(X, Wih0, bih0, bhh0, H1);
  scan_rnn<0><<<dim3(256), dim3(256), 0, stream>>>(H1, Whh0, nullptr, nullptr, nullptr,
                                                   PH, CT, nullptr);
  scan_rnn<1><<<dim3(256), dim3(256), 0, stream>>>(H1, Whh1, WFL, bih1, bhh1,
                                                   PH, CT + 128, HL);
  fc_k<<<dim3(BB), dim3(OO), 0, stream>>>(HL, fcw, fcb, out);
}

// Round 5
// 6911.756 us; speedup vs baseline: 1.9151x; 1.4892x over previous
//
#include <hip/hip_runtime.h>
#include <hip/hip_bf16.h>

// RNN_53145925320808 on MI355X (gfx950), 2-layer ReLU RNN + FC.
// R5: flag-ARRAY group barrier (per-block 64B-spaced flag store + wave-
// parallel ballot poll) replaces the 32-way same-address fetch_add convoy
// at the MALL (R4: 10.2us/step all-idle). Data exchange stays on relaxed
// agent-scope atomics (MALL-coherent, placement-independent).

#define TT 512
#define BB 256
#define HH 1024
#define II 512
#define OO 256

typedef __attribute__((ext_vector_type(4))) float f32x4;
typedef __attribute__((ext_vector_type(8))) short short8;
typedef __attribute__((ext_vector_type(8))) __bf16 bf16x8;
typedef unsigned long long u64;
typedef unsigned int u32;
typedef unsigned short u16;

#define WPL (32*64*64*8)      // shorts per Wih1 fragment-linear plane (2 MiB)
#define PLQ ((BB*HH)/4)       // u64 per exchange plane
#define CTSET 4096            // u32 per flag set: 8 groups x 32 blocks x 16

__device__ __forceinline__ u16 bf16_rne(float x){
  u32 u = __builtin_bit_cast(u32, x);
  u += 0x7fffu + ((u >> 16) & 1u);
  return (u16)(u >> 16);
}
__device__ __forceinline__ void split2(float x, u16 &hi, u16 &lo){
  hi = bf16_rne(x);
  float hf = __builtin_bit_cast(float, (u32)hi << 16);
  lo = bf16_rne(x - hf);
}
__device__ __forceinline__ float bf16_f(u32 v){
  return __builtin_bit_cast(float, v << 16);
}
__device__ __forceinline__ bf16x8 ld_frag16(const u16* p){
  short8 s = *reinterpret_cast<const short8*>(p);
  return __builtin_bit_cast(bf16x8, s);
}
__device__ __forceinline__ bf16x8 ld_frag_atomic(u64* q){
  u64 q0 = __hip_atomic_load(q,   __ATOMIC_RELAXED, __HIP_MEMORY_SCOPE_AGENT);
  u64 q1 = __hip_atomic_load(q+1, __ATOMIC_RELAXED, __HIP_MEMORY_SCOPE_AGENT);
  union { u64 u[2]; short8 s; } v; v.u[0]=q0; v.u[1]=q1;
  return __builtin_bit_cast(bf16x8, v.s);
}
__device__ __forceinline__ u64 pack4(u16 a, u16 b, u16 c, u16 d){
  return (u64)(((u32)b<<16)|a) | ((u64)(((u32)d<<16)|c) << 32);
}
__device__ __forceinline__ int swz(int byte){  // mix k-group bits (8-9) into bank bits (4-5)
  return byte ^ (((byte >> 8) & 3) << 4);
}

// ---------------------------------------------------------------------------
// gemm0: pre0 = X @ W_ih0^T + (b_ih0+b_hh0), X fp32 [B,T,I] rows (b*T+t),
// output bf16(rne) stored [t][b][n]. 128x128 tile, BK=32, 4 waves, hi/lo
// split x3 MFMA. LDS fragment-linear + XOR-swizzle -> conflict-free.
// ---------------------------------------------------------------------------
__global__ __launch_bounds__(256, 1)
void gemm0(const float* __restrict__ X, const float* __restrict__ W,
           const float* __restrict__ b1, const float* __restrict__ b2,
           u16* __restrict__ Out)
{
  constexpr int BK = 32, KT = II / BK;
  __shared__ __align__(16) u16 lA[2][2][128*32];
  __shared__ __align__(16) u16 lB[2][2][128*32];

  const int bid  = blockIdx.x;
  const int nt   = bid & 7;
  const long mt  = bid >> 3;
  const long row_base = mt * 128;
  const int n0   = nt * 128;
  const int tid  = threadIdx.x;
  const int lane = tid & 63;
  const int wave = tid >> 6;
  const int wm = wave >> 1, wn = wave & 1;

  const int sr = tid >> 3;
  const int sk = (tid & 7) << 2;
  const int lq = ((sk >> 3) & 3) << 4;
  const int su = (sk & 7) >> 1;        // u32 slot within lane: 0 or 2

  f32x4 acc[4][4];
  #pragma unroll
  for (int i=0;i<4;++i)
    #pragma unroll
    for (int j=0;j<4;++j) acc[i][j] = (f32x4)0.f;

  f32x4 va[4], vb[4];

  auto ldAB = [&](int kt){
    #pragma unroll
    for (int it=0; it<4; ++it){
      long m = row_base + it*32 + sr;
      va[it] = *reinterpret_cast<const f32x4*>(X + m*II + (long)kt*BK + sk);
      long n = n0 + it*32 + sr;
      vb[it] = *reinterpret_cast<const f32x4*>(W + n*II + (long)kt*BK + sk);
    }
  };
  auto wrAB = [&](int buf){
    char* AH = (char*)lA[buf][0];
    char* AL = (char*)lA[buf][1];
    char* BH = (char*)lB[buf][0];
    char* BL = (char*)lB[buf][1];
    #pragma unroll
    for (int it=0; it<4; ++it){
      int mloc = it*32 + sr;
      int byt = (mloc>>4)*1024 + ((mloc&15)|lq)*16 + su*4;   // 8B aligned
      int bs = swz(byt);
      u16 h0,l0,h1,l1,h2,l2,h3,l3;
      split2(va[it].x,h0,l0); split2(va[it].y,h1,l1);
      split2(va[it].z,h2,l2); split2(va[it].w,h3,l3);
      *reinterpret_cast<u64*>(AH + bs) = pack4(h0,h1,h2,h3);
      *reinterpret_cast<u64*>(AL + bs) = pack4(l0,l1,l2,l3);
      u16 g0,m0,g1,m1,g2,m2,g3,m3;
      split2(vb[it].x,g0,m0); split2(vb[it].y,g1,m1);
      split2(vb[it].z,g2,m2); split2(vb[it].w,g3,m3);
      *reinterpret_cast<u64*>(BH + bs) = pack4(g0,g1,g2,g3);
      *reinterpret_cast<u64*>(BL + bs) = pack4(m0,m1,m2,m3);
    }
  };

  ldAB(0); wrAB(0);
  for (int kt = 0; kt < KT; ++kt){
    __syncthreads();
    const bool more = (kt + 1 < KT);
    if (more) ldAB(kt+1);
    const char* Ah = (const char*)lA[kt&1][0];
    const char* Al = (const char*)lA[kt&1][1];
    const char* Bh = (const char*)lB[kt&1][0];
    const char* Bl = (const char*)lB[kt&1][1];
    bf16x8 ah[4], al[4], bh[4], bl[4];
    #pragma unroll
    for (int mi=0; mi<4; ++mi){
      int ob = swz(((wm*4+mi)*64 + lane)*16);
      ah[mi] = ld_frag16((const u16*)(Ah + ob));
      al[mi] = ld_frag16((const u16*)(Al + ob));
    }
    #pragma unroll
    for (int ni=0; ni<4; ++ni){
      int ob = swz(((wn*4+ni)*64 + lane)*16);
      bh[ni] = ld_frag16((const u16*)(Bh + ob));
      bl[ni] = ld_frag16((const u16*)(Bl + ob));
    }
    #pragma unroll
    for (int mi=0; mi<4; ++mi)
      #pragma unroll
      for (int ni=0; ni<4; ++ni){
        acc[mi][ni] = __builtin_amdgcn_mfma_f32_16x16x32_bf16(ah[mi], bh[ni], acc[mi][ni], 0,0,0);
        acc[mi][ni] = __builtin_amdgcn_mfma_f32_16x16x32_bf16(ah[mi], bl[ni], acc[mi][ni], 0,0,0);
        acc[mi][ni] = __builtin_amdgcn_mfma_f32_16x16x32_bf16(al[mi], bh[ni], acc[mi][ni], 0,0,0);
      }
    if (more) wrAB((kt+1)&1);
  }

  #pragma unroll
  for (int ni=0; ni<4; ++ni){
    int n = n0 + wn*64 + ni*16 + (lane & 15);
    float bs = b1[n] + b2[n];
    #pragma unroll
    for (int mi=0; mi<4; ++mi){
      #pragma unroll
      for (int j=0; j<4; ++j){
        long r = row_base + wm*64 + mi*16 + ((lane>>4)*4) + j;
        long bb = r >> 9;          // r = b*T + t, T=512
        long t  = r & (TT-1);
        Out[(t*BB + bb)*HH + n] = bf16_rne(acc[mi][ni][j] + bs);
      }
    }
  }
}

// ---------------------------------------------------------------------------
// prep_wih1: W_ih1 fp32 [H,H] -> two bf16 fragment-linear planes (hi, lo).
// ---------------------------------------------------------------------------
__global__ __launch_bounds__(256)
void prep_wih1(const float* __restrict__ W, u16* __restrict__ Wfl){
  int f  = blockIdx.x*256 + threadIdx.x;   // [0, 1024*128)
  int n  = f >> 7;
  int k8 = (f & 127) << 3;
  f32x4 w0 = *reinterpret_cast<const f32x4*>(W + (long)n*HH + k8);
  f32x4 w1 = *reinterpret_cast<const f32x4*>(W + (long)n*HH + k8 + 4);
  short8 hs, ls;
  u16 h, l;
  split2(w0.x,h,l); hs[0]=(short)h; ls[0]=(short)l;
  split2(w0.y,h,l); hs[1]=(short)h; ls[1]=(short)l;
  split2(w0.z,h,l); hs[2]=(short)h; ls[2]=(short)l;
  split2(w0.w,h,l); hs[3]=(short)h; ls[3]=(short)l;
  split2(w1.x,h,l); hs[4]=(short)h; ls[4]=(short)l;
  split2(w1.y,h,l); hs[5]=(short)h; ls[5]=(short)l;
  split2(w1.z,h,l); hs[6]=(short)h; ls[6]=(short)l;
  split2(w1.w,h,l); hs[7]=(short)h; ls[7]=(short)l;
  int gn = n >> 5, nl = n & 31;
  int fi = (nl>>4)*32 + (k8>>5);
  int ln = (nl&15) | (((k8>>3)&3)<<4);
  long base = (((long)gn*64 + fi)*64 + ln)*8;
  *reinterpret_cast<short8*>(Wfl + base)        = hs;
  *reinterpret_cast<short8*>(Wfl + WPL + base)  = ls;
}

// ---------------------------------------------------------------------------
// scan<L>: 256 blocks = 8 batch-groups x 32 col-slices. W_hh slice hi/lo in
// LDS. h exchanged via fragment-linear bf16 planes (relaxed agent atomics =
// MALL-coherent). Barrier: per-block flag store (own 64B line, no RMW) +
// wave-0 parallel ballot poll of all 32 sibling flags.
// L==1 fuses pre1 = h1[t] @ W_ih1^T with A-fragments prefetched across steps.
// ---------------------------------------------------------------------------
template<int L>
__global__ __launch_bounds__(256, 1)
void scan_rnn(u16* __restrict__ h1,
              const float* __restrict__ Whh,
              const u16* __restrict__ Wfl,
              const float* __restrict__ bih,
              const float* __restrict__ bhh,
              u64* PhQ, u32* ctr, float* __restrict__ h_last)
{
  __shared__ __align__(16) u16 lWh[32*1024];
  __shared__ __align__(16) u16 lWl[32*1024];
  __shared__ __align__(16) float lred[4][32][36];

  const int bid = blockIdx.x;
  const int gm = bid & 7;        // batch group -> XCD-local under bid%8 round-robin
  const int gn = bid >> 3;       // col slice
  const int tid = threadIdx.x;
  const int lane = tid & 63;
  const int kq = tid >> 6;

  { // stage W_hh slice -> LDS hi/lo fragment-linear (one-time)
    u32* WH = (u32*)lWh;
    u32* WL = (u32*)lWl;
    #pragma unroll 4
    for (int it=0; it<32; ++it){
      int f = it*256 + tid;
      int nl = f >> 8;
      int k4 = (f & 255) << 2;
      f32x4 w = *reinterpret_cast<const f32x4*>(Whh + (long)(gn*32 + nl)*HH + k4);
      int base = (((nl>>4)*32 + (k4>>5))*64 + ((nl&15) | (((k4>>3)&3)<<4)))*4 + ((k4&7)>>1);
      u16 h0,l0,h1_,l1,h2,l2,h3,l3;
      split2(w.x,h0,l0); split2(w.y,h1_,l1); split2(w.z,h2,l2); split2(w.w,h3,l3);
      WH[base]   = ((u32)h1_<<16)|h0;  WH[base+1] = ((u32)h3<<16)|h2;
      WL[base]   = ((u32)l1<<16)|l0;   WL[base+1] = ((u32)l3<<16)|l2;
    }
  }
  __syncthreads();

  const int fr  = tid >> 3;
  const int fcl = (tid & 7) << 2;
  const long b_out = gm*32 + fr;
  const int  n_out = gn*32 + fcl;
  const long plq = (long)((((b_out>>4)*32 + (n_out>>5))*64
                    + ((b_out&15) | (((n_out>>3)&3)<<4)))*8 + (n_out&7)) >> 2;
  u32* flg_own = ctr + (gm*32 + gn)*16;   // this block's flag (64B line)
  u32* flg_grp = ctr + gm*32*16;          // group flag base

  const int r_lane = lane & 15;
  const int kg8    = (lane >> 4) * 8;
  long rowoff[2];
  #pragma unroll
  for (int mi=0; mi<2; ++mi)
    rowoff[mi] = (long)((gm*2+mi)*16 + r_lane)*HH + kg8;

  f32x4 bias = (f32x4)0.f;
  if constexpr (L == 1){
    f32x4 b1v = *reinterpret_cast<const f32x4*>(bih + n_out);
    f32x4 b2v = *reinterpret_cast<const f32x4*>(bhh + n_out);
    bias = b1v + b2v;
  }

  // L1: A-fragments of h1[t], prefetched one step ahead (no cross-block dep)
  bf16x8 a1r[2][8];
  auto ld_a1 = [&](int t){
    const long pb = (long)t * BB * HH;
    #pragma unroll
    for (int kc=0; kc<8; ++kc)
      #pragma unroll
      for (int mi=0; mi<2; ++mi)
        a1r[mi][kc] = ld_frag16(h1 + pb + rowoff[mi] + (kq*8+kc)*32);
  };
  if constexpr (L == 1) ld_a1(0);

  for (int t=0; t<TT; ++t){
    const long pbase = (long)t * BB * HH;
    float p0=0.f,p1=0.f,p2=0.f,p3=0.f;
    if constexpr (L == 0){
      u64 pv = *reinterpret_cast<const u64*>(h1 + pbase + b_out*HH + n_out);
      p0 = bf16_f((u32)(pv & 0xffff));
      p1 = bf16_f((u32)((pv>>16) & 0xffff));
      p2 = bf16_f((u32)((pv>>32) & 0xffff));
      p3 = bf16_f((u32)((pv>>48) & 0xffff));
    }
    const int wb = t & 1, rb = wb ^ 1;

    f32x4 acc[2][2];
    acc[0][0]=(f32x4)0.f; acc[0][1]=(f32x4)0.f; acc[1][0]=(f32x4)0.f; acc[1][1]=(f32x4)0.f;

    if (t > 0){   // recurrent term: h_{t-1} @ W_hh^T (hi/lo B x2 MFMA)
      u64* Aq = PhQ + (long)rb*PLQ;
      #pragma unroll
      for (int kc=0; kc<8; ++kc){
        const int kcg = kq*8 + kc;
        bf16x8 a2[2], bh[2], bl[2];
        #pragma unroll
        for (int mi=0; mi<2; ++mi)
          a2[mi] = ld_frag_atomic(Aq + ((long)((gm*2+mi)*32 + kcg)*64 + lane)*2);
        #pragma unroll
        for (int ni=0; ni<2; ++ni){
          int off = ((ni*32 + kcg)*64 + lane)*8;
          bh[ni] = ld_frag16(lWh + off);
          bl[ni] = ld_frag16(lWl + off);
        }
        #pragma unroll
        for (int mi=0; mi<2; ++mi)
          #pragma unroll
          for (int ni=0; ni<2; ++ni){
            acc[mi][ni] = __builtin_amdgcn_mfma_f32_16x16x32_bf16(a2[mi], bh[ni], acc[mi][ni],0,0,0);
            acc[mi][ni] = __builtin_amdgcn_mfma_f32_16x16x32_bf16(a2[mi], bl[ni], acc[mi][ni],0,0,0);
          }
      }
    }

    if constexpr (L == 1){   // fused pre1 = h1[t] @ W_ih1^T (prefetched A)
      #pragma unroll
      for (int kc=0; kc<8; ++kc){
        const int kcg = kq*8 + kc;
        bf16x8 wh[2], wl[2];
        #pragma unroll
        for (int ni=0; ni<2; ++ni){
          long woff = (((long)gn*64 + (ni*32 + kcg))*64 + lane)*8;
          wh[ni] = ld_frag16(Wfl + woff);
          wl[ni] = ld_frag16(Wfl + WPL + woff);
        }
        #pragma unroll
        for (int mi=0; mi<2; ++mi)
          #pragma unroll
          for (int ni=0; ni<2; ++ni){
            acc[mi][ni] = __builtin_amdgcn_mfma_f32_16x16x32_bf16(a1r[mi][kc], wh[ni], acc[mi][ni],0,0,0);
            acc[mi][ni] = __builtin_amdgcn_mfma_f32_16x16x32_bf16(a1r[mi][kc], wl[ni], acc[mi][ni],0,0,0);
          }
      }
      if (t + 1 < TT) ld_a1(t+1);   // prefetch next step's A, hidden under finish+barrier
    }

    const bool red = (L == 1) || (t > 0);
    if (red){
      #pragma unroll
      for (int mi=0; mi<2; ++mi)
        #pragma unroll
        for (int ni=0; ni<2; ++ni)
          #pragma unroll
          for (int j=0; j<4; ++j)
            lred[kq][mi*16 + (lane>>4)*4 + j][ni*16 + (lane&15)] = acc[mi][ni][j];
    }
    __syncthreads();

    float s0=0.f, s1=0.f, s2=0.f, s3=0.f;
    if (red){
      #pragma unroll
      for (int w=0; w<4; ++w){
        const f32x4 v = *reinterpret_cast<const f32x4*>(&lred[w][fr][fcl]);
        s0 += v.x; s1 += v.y; s2 += v.z; s3 += v.w;
      }
    }
    float h0, h1v, h2, h3;
    if constexpr (L == 0){
      h0 = fmaxf(s0 + p0, 0.f); h1v = fmaxf(s1 + p1, 0.f);
      h2 = fmaxf(s2 + p2, 0.f); h3  = fmaxf(s3 + p3, 0.f);
    } else {
      h0 = fmaxf(s0 + bias.x, 0.f); h1v = fmaxf(s1 + bias.y, 0.f);
      h2 = fmaxf(s2 + bias.z, 0.f); h3  = fmaxf(s3 + bias.w, 0.f);
    }
    const u64 hv = (u64)bf16_rne(h0) | ((u64)bf16_rne(h1v)<<16)
                 | ((u64)bf16_rne(h2)<<32) | ((u64)bf16_rne(h3)<<48);
    __hip_atomic_store(PhQ + (long)wb*PLQ + plq, hv,
                       __ATOMIC_RELAXED, __HIP_MEMORY_SCOPE_AGENT);
    if constexpr (L == 0){
      *reinterpret_cast<u64*>(h1 + pbase + b_out*HH + n_out) = hv;  // in place over pre0
    } else {
      if (t == TT-1){
        f32x4 hvv; hvv.x=h0; hvv.y=h1v; hvv.z=h2; hvv.w=h3;
        *reinterpret_cast<f32x4*>(h_last + b_out*HH + n_out) = hvv;
      }
    }
    __syncthreads();   // all waves' stores drained (vmcnt0 at MALL) before flag
    const u32 tgt = (u32)(t + 1);
    if (tid == 0)      // own flag, own cache line: plain store, no RMW convoy
      __hip_atomic_store(flg_own, tgt, __ATOMIC_RELAXED, __HIP_MEMORY_SCOPE_AGENT);
    if (tid < 64){     // wave 0: 32 lanes poll 32 sibling flags in parallel
      bool ok;
      do {
        u32 v = tgt;
        if (lane < 32)
          v = __hip_atomic_load(flg_grp + lane*16, __ATOMIC_RELAXED, __HIP_MEMORY_SCOPE_AGENT);
        ok = (v >= tgt);
      } while (!__all(ok));
    }
    __syncthreads();
  }
}

__global__ void init_ws(u32* ctr){ ctr[blockIdx.x*256 + threadIdx.x] = 0u; }

__global__ __launch_bounds__(256)
void beacon(float* out, int n){
  for (int i = blockIdx.x*256 + threadIdx.x; i < n; i += 256*256) out[i] = 1.0e6f;
}

__global__ __launch_bounds__(256)
void fc_k(const float* __restrict__ h, const float* __restrict__ w,
          const float* __restrict__ bsc, float* __restrict__ out){
  const int b = blockIdx.x;
  const int o = threadIdx.x;
  const f32x4* hp = reinterpret_cast<const f32x4*>(h + (long)b*HH);
  const f32x4* wp = reinterpret_cast<const f32x4*>(w + (long)o*HH);
  float acc = 0.f;
  #pragma unroll 8
  for (int i=0; i<HH/4; ++i){
    f32x4 a = hp[i], c = wp[i];
    acc += a.x*c.x + a.y*c.y + a.z*c.z + a.w*c.w;
  }
  out[(long)b*OO + o] = acc + bsc[o];
}

extern "C" void kernel_launch(void* const* d_in, const int* in_sizes, int n_in,
                              void* d_out, int out_size, void* d_ws, size_t ws_size,
                              hipStream_t stream)
{
  const float* X    = (const float*)d_in[0];
  const float* Wih0 = (const float*)d_in[1];
  const float* Whh0 = (const float*)d_in[2];
  const float* bih0 = (const float*)d_in[3];
  const float* bhh0 = (const float*)d_in[4];
  const float* Wih1 = (const float*)d_in[5];
  const float* Whh1 = (const float*)d_in[6];
  const float* bih1 = (const float*)d_in[7];
  const float* bhh1 = (const float*)d_in[8];
  const float* fcw  = (const float*)d_in[9];
  const float* fcb  = (const float*)d_in[10];
  float* out = (float*)d_out;
  char* ws = (char*)d_ws;

  size_t off = 0;
  u16* H1  = (u16*)(ws + off); off += (size_t)TT*BB*HH*2;   // 256 MiB: pre0 -> h1 (bf16)
  u16* WFL = (u16*)(ws + off); off += (size_t)2*WPL*2;      // 4 MiB: Wih1 hi/lo planes
  u64* PH  = (u64*)(ws + off); off += (size_t)2*PLQ*8;      // 1 MiB: exchange planes
  float* HL = (float*)(ws + off); off += (size_t)BB*HH*4;   // 1 MiB
  u32* CT  = (u32*)(ws + off); off += (size_t)2*CTSET*4;    // 32 KiB flags (2 sets)

  if (ws_size < off){   // ws too small: 1e6 beacon signals this path distinctly
    beacon<<<dim3(256), dim3(256), 0, stream>>>(out, out_size);
    return;
  }

  init_ws<<<dim3(32), dim3(256), 0, stream>>>(CT);
  prep_wih1<<<dim3(512), dim3(256), 0, stream>>>(Wih1, WFL);
  gemm0<<<dim3((131072/128)*(HH/128)), dim3(256), 0, stream>>>(X, Wih0, bih0, bhh0, H1);
  scan_rnn<0><<<dim3(256), dim3(256), 0, stream>>>(H1, Whh0, nullptr, nullptr, nullptr,
                                                   PH, CT, nullptr);
  scan_rnn<1><<<dim3(256), dim3(256), 0, stream>>>(H1, Whh1, WFL, bih1, bhh1,
                                                   PH, CT + CTSET, HL);
  fc_k<<<dim3(BB), dim3(OO), 0, stream>>>(HL, fcw, fcb, out);
}